// Round 1
// baseline (1159.297 us; speedup 1.0000x reference)
//
#include <hip/hip_runtime.h>
#include <stdint.h>

#define Hh 128
#define Aa 16
#define Tt 4
#define K1 144
#define W1T_LD 168   // pad: stride 336B -> bank advance 20 dw -> 2-way (free)
#define WG_LD  136   // pad: stride 272B -> bank advance 4 dw  -> 2-way (free)

typedef float f32x4 __attribute__((ext_vector_type(4)));
typedef __bf16 bf16x8 __attribute__((ext_vector_type(8)));
typedef unsigned short u16x8 __attribute__((ext_vector_type(8)));
typedef unsigned short u16x4 __attribute__((ext_vector_type(4)));
typedef unsigned short u16x2 __attribute__((ext_vector_type(2)));

static __device__ __forceinline__ unsigned short f2bf(float f) {
    unsigned u = __builtin_bit_cast(unsigned, f);
    u += 0x7fffu + ((u >> 16) & 1u);   // RNE
    return (unsigned short)(u >> 16);
}

static __device__ __forceinline__ float bf2f(unsigned short u) {
    return __builtin_bit_cast(float, (unsigned)u << 16);
}

static __device__ __forceinline__ bf16x8 pack8(const float* __restrict__ x) {
    f32x4 a = *(const f32x4*)x;
    f32x4 b = *(const f32x4*)(x + 4);
    u16x8 t;
    t[0] = f2bf(a[0]); t[1] = f2bf(a[1]); t[2] = f2bf(a[2]); t[3] = f2bf(a[3]);
    t[4] = f2bf(b[0]); t[5] = f2bf(b[1]); t[6] = f2bf(b[2]); t[7] = f2bf(b[3]);
    return __builtin_bit_cast(bf16x8, t);
}

static __device__ __forceinline__ bf16x8 zero_bf8() {
    u16x8 z = {0, 0, 0, 0, 0, 0, 0, 0};
    return __builtin_bit_cast(bf16x8, z);
}

// ============ fused bf16 pre-cast of all 5 fp32 arrays (1 launch, was 5)
__global__ void cast_all_kernel(
    const float* __restrict__ h, const float* __restrict__ W1,
    const float* __restrict__ W2, const float* __restrict__ wih,
    const float* __restrict__ whh,
    unsigned short* __restrict__ h_bf, unsigned short* __restrict__ W1bf,
    unsigned short* __restrict__ W2bf, unsigned short* __restrict__ wihb,
    unsigned short* __restrict__ whhb,
    int n0, int n1, int n2, int n3, int n4)   // cumulative float4 boundaries
{
    int i = blockIdx.x * blockDim.x + threadIdx.x;
    if (i >= n4) return;
    const float* s; unsigned short* d; int off;
    if (i < n0)      { s = h;   d = h_bf; off = i; }
    else if (i < n1) { s = W1;  d = W1bf; off = i - n0; }
    else if (i < n2) { s = W2;  d = W2bf; off = i - n1; }
    else if (i < n3) { s = wih; d = wihb; off = i - n2; }
    else             { s = whh; d = whhb; off = i - n3; }
    f32x4 v = *(const f32x4*)(s + (size_t)off * 4);
    u16x4 o;
    o[0] = f2bf(v[0]); o[1] = f2bf(v[1]); o[2] = f2bf(v[2]); o[3] = f2bf(v[3]);
    *(u16x4*)(d + (size_t)off * 4) = o;
}

// ============ dual bucketing: bins [0,4N) by (type,dst), bins [4N,8N) by (type,src)
__global__ void hist_kernel(const int* __restrict__ et, const int* __restrict__ eidx,
                            int E, int N, int* __restrict__ cnt, unsigned* __restrict__ rank) {
    for (int i = blockIdx.x * blockDim.x + threadIdx.x; i < E; i += gridDim.x * blockDim.x) {
        int tt = et[i];
        unsigned rD = (unsigned)atomicAdd(&cnt[tt * N + eidx[E + i]], 1);
        unsigned rS = (unsigned)atomicAdd(&cnt[4 * N + tt * N + eidx[i]], 1);
        rank[i] = rD | (rS << 16);
    }
}

// per-1024-chunk block sums
__global__ void scanA_kernel(const int* __restrict__ deg2, int nb, int* __restrict__ bsum) {
    __shared__ int red[256];
    const int t = threadIdx.x;
    const int i0 = blockIdx.x * 1024 + t * 4;
    int s = 0;
    #pragma unroll
    for (int j = 0; j < 4; j++) if (i0 + j < nb) s += deg2[i0 + j];
    red[t] = s; __syncthreads();
    for (int d = 128; d > 0; d >>= 1) {
        if (t < d) red[t] += red[t + d];
        __syncthreads();
    }
    if (t == 0) bsum[blockIdx.x] = red[0];
}

// single-block exclusive scan of block sums (nblocks <= 512); also closes dst rowptr
__global__ void scanB_kernel(int* __restrict__ bsum, int nblocks,
                             int* __restrict__ rowptrD, int fourN, int E) {
    __shared__ int ts[512];
    const int t = threadIdx.x;
    int v = (t < nblocks) ? bsum[t] : 0;
    ts[t] = v; __syncthreads();
    for (int d = 1; d < 512; d <<= 1) {
        int x = (t >= d) ? ts[t - d] : 0;
        __syncthreads();
        ts[t] += x;
        __syncthreads();
    }
    if (t < nblocks) bsum[t] = ts[t] - v;
    if (t == 0) rowptrD[fourN] = E;
}

// per-chunk exclusive scan + global offset
__global__ void scanC_kernel(int* __restrict__ cur, int nb, int fourN,
                             const int* __restrict__ bsum, int* __restrict__ rowptrD) {
    __shared__ int ts[256];
    const int t = threadIdx.x;
    const int i0 = blockIdx.x * 1024 + t * 4;
    int v[4];
    #pragma unroll
    for (int j = 0; j < 4; j++) v[j] = (i0 + j < nb) ? cur[i0 + j] : 0;
    int s = v[0] + v[1] + v[2] + v[3];
    ts[t] = s; __syncthreads();
    for (int d = 1; d < 256; d <<= 1) {
        int x = (t >= d) ? ts[t - d] : 0;
        __syncthreads();
        ts[t] += x;
        __syncthreads();
    }
    int run = bsum[blockIdx.x] + ts[t] - s;
    #pragma unroll
    for (int j = 0; j < 4; j++) {
        if (i0 + j < nb) {
            if (i0 + j < fourN) rowptrD[i0 + j] = run;
            cur[i0 + j] = run;
            run += v[j];
        }
    }
}

// atomic-free placement
__global__ void fill2_kernel(const int* __restrict__ et, const int* __restrict__ eidx,
                             int E, int N, const int* __restrict__ binstart,
                             const unsigned* __restrict__ rank, int4* __restrict__ rec) {
    for (int i = blockIdx.x * blockDim.x + threadIdx.x; i < E; i += gridDim.x * blockDim.x) {
        int tt = et[i];
        int d = eidx[E + i], s = eidx[i];
        unsigned r = rank[i];
        int posD = binstart[tt * N + d] + (int)(r & 0xffffu);
        int posS = binstart[4 * N + tt * N + s] + (int)(r >> 16) - E;
        rec[posS] = make_int4(s, i, posD, 0);
    }
}

// ---------------- layer 1: edges in (type,src) order -> sequential h gather;
// DIRECT per-lane stores to (type,dst) position: lane (q,l15) reg i of acc[mt]
// holds channel mt*16+q*4+i of edge l15, and every q-group loaded the same 16
// records -> each lane already has its edge's posD. One u16x4 store per (g,mt)
// covers a full 32B sector of the row; 8 mt-stores complete the 256B row while
// its L2 lines are hot. No LDS transpose, no waitcnt windows, no shfl.
// LDS = 43008 + 512 = 43520 B -> 3 blocks/CU (was 60928 -> 2).
__global__ __launch_bounds__(512, 6) void l1_kernel(
    const unsigned short* __restrict__ h_bf, const int4* __restrict__ rec,
    const float* __restrict__ eattr, const unsigned short* __restrict__ W1bf,
    const float* __restrict__ b1, const int* __restrict__ rowptrD,
    unsigned short* __restrict__ Yg, int N)
{
    __shared__ unsigned short W1T[128 * W1T_LD];
    __shared__ float b1s[128];
    const int t = blockIdx.x & 3;
    const int lb = blockIdx.x >> 2;
    const int nbk = gridDim.x >> 2;
    const int tid = threadIdx.x;

    // stage W1^T: vectorized u16x8 global reads, 8 scalar LDS writes (transpose).
    // LDS write banks: +W1T_LD u16 per j = +84B*... = +20 dw mod 32 -> all distinct.
    for (int idx = tid; idx < (K1 * Hh) / 8; idx += 512) {
        int k = idx >> 4, n0 = (idx & 15) * 8;
        u16x8 v = *(const u16x8*)&W1bf[((size_t)t * K1 + k) * Hh + n0];
        #pragma unroll
        for (int j = 0; j < 8; j++) W1T[(n0 + j) * W1T_LD + k] = v[j];
    }
    for (int idx = tid; idx < Hh * 3; idx += 512) {   // zero pad k=144..167, 3 x u16x8/row
        int n = idx / 3, c = (idx % 3) * 8;
        u16x8 z = {0, 0, 0, 0, 0, 0, 0, 0};
        *(u16x8*)&W1T[n * W1T_LD + K1 + c] = z;
    }
    if (tid < 128) b1s[tid] = b1[t * Hh + tid];
    __syncthreads();

    const int tstart = rowptrD[t * N];
    const int tend = rowptrD[(t + 1) * N];
    const int cnt = tend - tstart;
    const int ntiles = (cnt + 255) >> 8;
    const int w = tid >> 6, lane = tid & 63;
    const int l15 = lane & 15, q = lane >> 4;

    for (int tile = lb; tile < ntiles; tile += nbk) {
        const int p0 = tstart + tile * 256 + w * 32;
        const int pa = p0 + l15, pb = p0 + 16 + l15;
        const bool va = pa < tend, vb = pb < tend;
        const int4 ra = rec[va ? pa : tstart];
        const int4 rb = rec[vb ? pb : tstart];
        const int sa = ra.x, sb = rb.x;
        const int ea = ra.y, eb = rb.y;
        const int ypa = ra.z, ypb = rb.z;
        const unsigned short* __restrict__ hA = h_bf + (size_t)sa * Hh;
        const unsigned short* __restrict__ hB = h_bf + (size_t)sb * Hh;

        f32x4 acc[8][2];
        #pragma unroll
        for (int mt = 0; mt < 8; mt++) {
            acc[mt][0] = (f32x4){0.f, 0.f, 0.f, 0.f};
            acc[mt][1] = (f32x4){0.f, 0.f, 0.f, 0.f};
        }

        #pragma unroll
        for (int ks = 0; ks < 5; ks++) {
            const int k0 = ks * 32;
            bf16x8 fb_a, fb_b;
            if (ks < 4) {
                fb_a = __builtin_bit_cast(bf16x8, *(const u16x8*)(hA + k0 + q * 8));
                fb_b = __builtin_bit_cast(bf16x8, *(const u16x8*)(hB + k0 + q * 8));
            } else if (q < 2) {
                fb_a = pack8(eattr + (size_t)ea * Aa + q * 8);
                fb_b = pack8(eattr + (size_t)eb * Aa + q * 8);
            } else {
                fb_a = zero_bf8();
                fb_b = zero_bf8();
            }
            #pragma unroll
            for (int mt = 0; mt < 8; mt++) {
                bf16x8 fa = *(const bf16x8*)&W1T[(mt * 16 + l15) * W1T_LD + k0 + q * 8];
                acc[mt][0] = __builtin_amdgcn_mfma_f32_16x16x32_bf16(fa, fb_a, acc[mt][0], 0, 0, 0);
                acc[mt][1] = __builtin_amdgcn_mfma_f32_16x16x32_bf16(fa, fb_b, acc[mt][1], 0, 0, 0);
            }
        }

        // epilogue: bias+relu+cvt, direct 8B/lane stores (full 32B sectors)
        #pragma unroll
        for (int g = 0; g < 2; g++) {
            if (g ? vb : va) {
                unsigned short* __restrict__ o = Yg + (size_t)(g ? ypb : ypa) * Hh + q * 4;
                #pragma unroll
                for (int mt = 0; mt < 8; mt++) {
                    f32x4 bias = *(const f32x4*)&b1s[mt * 16 + q * 4];
                    u16x4 y;
                    #pragma unroll
                    for (int i = 0; i < 4; i++) {
                        float v = acc[mt][g][i] + bias[i];
                        y[i] = f2bf(v > 0.f ? v : 0.f);
                    }
                    *(u16x4*)(o + mt * 16) = y;
                }
            }
        }
    }
}

// ---------------- fused segment-sum + second GEMM (unchanged)
__global__ __launch_bounds__(256) void zgemm_kernel(
    const unsigned short* __restrict__ Yg, const int* __restrict__ rowptrD,
    const unsigned short* __restrict__ W2bf, const float* __restrict__ b2,
    unsigned short* __restrict__ msgb, int N)
{
    __shared__ unsigned short W2T[128 * WG_LD];
    __shared__ float b2s[512];
    __shared__ int cntS[4 * 64];
    const int tid = threadIdx.x;
    const int w = tid >> 6, lane = tid & 63;
    const int l15 = lane & 15, q = lane >> 4;
    const int nodebase = blockIdx.x * 64 + w * 16;
    const int nA = min(nodebase + l15, N - 1);

    if (tid < 512) {
        b2s[tid] = b2[tid];
        b2s[tid + 256] = b2[tid + 256];
    }

    f32x4 acc[8];
    #pragma unroll
    for (int ct = 0; ct < 8; ct++) acc[ct] = (f32x4){0.f, 0.f, 0.f, 0.f};

    for (int t = 0; t < Tt; t++) {
        __syncthreads();
        for (int idx = tid; idx < Hh * Hh; idx += 256) {
            int k = idx >> 7, n = idx & 127;
            W2T[n * WG_LD + k] = W2bf[((size_t)t * Hh + k) * Hh + n];
        }
        __syncthreads();

        const int seg = rowptrD[(size_t)t * N + nA];
        const int len = rowptrD[(size_t)t * N + nA + 1] - seg;
        cntS[w * 64 + t * 16 + l15] = len;

        float asum[32];
        #pragma unroll
        for (int i = 0; i < 32; i++) asum[i] = 0.f;
        for (int j = 0; j < len; j++) {
            const unsigned short* __restrict__ yr = Yg + (size_t)(seg + j) * Hh;
            #pragma unroll
            for (int ks = 0; ks < 4; ks++) {
                u16x8 yv = *(const u16x8*)(yr + ks * 32 + q * 8);
                #pragma unroll
                for (int e = 0; e < 8; e++) asum[ks * 8 + e] += bf2f(yv[e]);
            }
        }

        #pragma unroll
        for (int ks = 0; ks < 4; ks++) {
            u16x8 fr;
            #pragma unroll
            for (int e = 0; e < 8; e++) fr[e] = f2bf(asum[ks * 8 + e]);
            bf16x8 fa = __builtin_bit_cast(bf16x8, fr);
            #pragma unroll
            for (int ct = 0; ct < 8; ct++) {
                bf16x8 fb = *(const bf16x8*)&W2T[(ct * 16 + l15) * WG_LD + ks * 32 + q * 8];
                acc[ct] = __builtin_amdgcn_mfma_f32_16x16x32_bf16(fa, fb, acc[ct], 0, 0, 0);
            }
        }
    }
    __syncthreads();

    #pragma unroll
    for (int ct = 0; ct < 8; ct++) {
        const int c = ct * 16 + l15;
        #pragma unroll
        for (int i = 0; i < 4; i++) {
            int node = nodebase + q * 4 + i;
            if (node < N) {
                float bias = 0.f;
                #pragma unroll
                for (int t = 0; t < Tt; t++)
                    bias += (float)cntS[w * 64 + t * 16 + q * 4 + i] * b2s[t * 128 + c];
                msgb[(size_t)node * Hh + c] = f2bf(acc[ct][i] + bias);
            }
        }
    }
}

// ---------------- GRU: fragments hoisted (msg/h read ONCE, bf16), vectorized staging
__global__ __launch_bounds__(512) void gru_kernel(
    const float* __restrict__ h, const unsigned short* __restrict__ h_bf,
    const unsigned short* __restrict__ msgb,
    const unsigned short* __restrict__ wihb, const unsigned short* __restrict__ whhb,
    const float* __restrict__ b_ih, const float* __restrict__ b_hh,
    float* __restrict__ out, int N)
{
    __shared__ unsigned short Wg[128 * WG_LD];
    const int tid = threadIdx.x;
    const int w = tid >> 6, lane = tid & 63;
    const int l15 = lane & 15, q = lane >> 4;
    const int nodebase = blockIdx.x * 128 + w * 16;
    const int nA = min(nodebase + l15, N - 1);

    // hoist A-fragments: msg + h rows read once each (bit-identical to pack8(fp32 h))
    bf16x8 fm[4], fh[4];
    #pragma unroll
    for (int ks = 0; ks < 4; ks++) {
        fm[ks] = __builtin_bit_cast(bf16x8, *(const u16x8*)(msgb + (size_t)nA * Hh + ks * 32 + q * 8));
        fh[ks] = __builtin_bit_cast(bf16x8, *(const u16x8*)(h_bf + (size_t)nA * Hh + ks * 32 + q * 8));
    }

    f32x4 gr[8], gz[8], gin[8], ghn[8];
    #pragma unroll
    for (int ct = 0; ct < 8; ct++) {
        gr[ct] = (f32x4){0.f, 0.f, 0.f, 0.f};
        gz[ct] = (f32x4){0.f, 0.f, 0.f, 0.f};
        gin[ct] = (f32x4){0.f, 0.f, 0.f, 0.f};
        ghn[ct] = (f32x4){0.f, 0.f, 0.f, 0.f};
    }

    auto stage = [&](const unsigned short* __restrict__ Ws, int gate) {
        __syncthreads();
        for (int idx = tid; idx < (Hh * Hh) / 8; idx += 512) {
            int o = idx >> 4, k8 = (idx & 15) * 8;
            *(u16x8*)&Wg[o * WG_LD + k8] =
                *(const u16x8*)&Ws[(size_t)gate * Hh * Hh + o * Hh + k8];
        }
        __syncthreads();
    };
    auto matmul = [&](f32x4* acc, const bf16x8* fa) {
        #pragma unroll
        for (int ks = 0; ks < 4; ks++) {
            #pragma unroll
            for (int ct = 0; ct < 8; ct++) {
                bf16x8 fb = *(const bf16x8*)&Wg[(ct * 16 + l15) * WG_LD + ks * 32 + q * 8];
                acc[ct] = __builtin_amdgcn_mfma_f32_16x16x32_bf16(fa[ks], fb, acc[ct], 0, 0, 0);
            }
        }
    };

    stage(wihb, 0); matmul(gr, fm);
    stage(whhb, 0); matmul(gr, fh);
    stage(wihb, 1); matmul(gz, fm);
    stage(whhb, 1); matmul(gz, fh);
    stage(wihb, 2); matmul(gin, fm);
    stage(whhb, 2); matmul(ghn, fh);

    #pragma unroll
    for (int ct = 0; ct < 8; ct++) {
        int c = ct * 16 + l15;
        float bir = b_ih[c],       bhr = b_hh[c];
        float biz = b_ih[128 + c], bhz = b_hh[128 + c];
        float bin = b_ih[256 + c], bhn = b_hh[256 + c];
        #pragma unroll
        for (int i = 0; i < 4; i++) {
            int node = nodebase + q * 4 + i;
            if (node < N) {
                float rv = 1.f / (1.f + __expf(-(gr[ct][i] + bir + bhr)));
                float zv = 1.f / (1.f + __expf(-(gz[ct][i] + biz + bhz)));
                float npre = gin[ct][i] + bin + rv * (ghn[ct][i] + bhn);
                float e2 = __expf(-2.f * npre);
                float nv = (1.f - e2) / (1.f + e2);
                float hv = h[(size_t)node * Hh + c];
                out[(size_t)node * Hh + c] = (1.f - zv) * nv + zv * hv;
            }
        }
    }
}

static inline size_t align256(size_t x) { return (x + 255) & ~(size_t)255; }

extern "C" void kernel_launch(void* const* d_in, const int* in_sizes, int n_in,
                              void* d_out, int out_size, void* d_ws, size_t ws_size,
                              hipStream_t stream)
{
    const float* h     = (const float*)d_in[0];
    const int*   eidx  = (const int*)d_in[1];
    const int*   et    = (const int*)d_in[2];
    const float* eattr = (const float*)d_in[3];
    const float* W1    = (const float*)d_in[4];
    const float* b1    = (const float*)d_in[5];
    const float* W2    = (const float*)d_in[6];
    const float* b2    = (const float*)d_in[7];
    const float* w_ih  = (const float*)d_in[8];
    const float* w_hh  = (const float*)d_in[9];
    const float* b_ih  = (const float*)d_in[10];
    const float* b_hh  = (const float*)d_in[11];

    const int N = in_sizes[0] / Hh;
    const int E = in_sizes[1] / 2;
    const int nb = 8 * N;
    const int sblocks = (nb + 1023) / 1024;

    char* p = (char*)d_ws;
    unsigned short* msgb = (unsigned short*)p; p += align256((size_t)N * Hh * sizeof(unsigned short));
    unsigned short* Yg = (unsigned short*)p;   p += align256((size_t)E * Hh * sizeof(unsigned short));
    int4* rec = (int4*)p;               p += align256((size_t)E * sizeof(int4));
    unsigned* rank = (unsigned*)p;      p += align256((size_t)E * sizeof(unsigned));
    int* rowptrD = (int*)p;             p += align256(((size_t)4 * N + 1) * sizeof(int));
    int* cur = (int*)p;                 p += align256((size_t)nb * sizeof(int));
    int* bsum = (int*)p;                p += align256(1024 * sizeof(int));
    unsigned short* h_bf = (unsigned short*)p; p += align256((size_t)N * Hh * sizeof(unsigned short));
    unsigned short* W1bf = (unsigned short*)p; p += align256((size_t)Tt * K1 * Hh * sizeof(unsigned short));
    unsigned short* W2bf = (unsigned short*)p; p += align256((size_t)Tt * Hh * Hh * sizeof(unsigned short));
    unsigned short* wihb = (unsigned short*)p; p += align256((size_t)3 * Hh * Hh * sizeof(unsigned short));
    unsigned short* whhb = (unsigned short*)p; p += align256((size_t)3 * Hh * Hh * sizeof(unsigned short));

    hipMemsetAsync(cur, 0, (size_t)nb * sizeof(int), stream);

    {
        int n4h = N * Hh / 4, n41 = Tt * K1 * Hh / 4, n42 = Tt * Hh * Hh / 4;
        int n4g = 3 * Hh * Hh / 4;
        int c0 = n4h, c1 = c0 + n41, c2 = c1 + n42, c3 = c2 + n4g, c4 = c3 + n4g;
        cast_all_kernel<<<(c4 + 255) / 256, 256, 0, stream>>>(
            h, W1, W2, w_ih, w_hh, h_bf, W1bf, W2bf, wihb, whhb, c0, c1, c2, c3, c4);
    }

    hist_kernel<<<1024, 256, 0, stream>>>(et, eidx, E, N, cur, rank);
    scanA_kernel<<<sblocks, 256, 0, stream>>>(cur, nb, bsum);
    scanB_kernel<<<1, 512, 0, stream>>>(bsum, sblocks, rowptrD, 4 * N, E);
    scanC_kernel<<<sblocks, 256, 0, stream>>>(cur, nb, 4 * N, bsum, rowptrD);
    fill2_kernel<<<1024, 256, 0, stream>>>(et, eidx, E, N, cur, rank, rec);

    l1_kernel<<<2048, 512, 0, stream>>>(h_bf, rec, eattr, W1bf, b1, rowptrD, Yg, N);
    zgemm_kernel<<<(N + 63) / 64, 256, 0, stream>>>(Yg, rowptrD, W2bf, b2, msgb, N);

    int gblocks = (N + 127) / 128;
    gru_kernel<<<gblocks, 512, 0, stream>>>(h, h_bf, msgb, wihb, whhb, b_ih, b_hh, (float*)d_out, N);
}

// Round 2
// 502.390 us; speedup vs baseline: 2.3076x; 2.3076x over previous
//
#include <hip/hip_runtime.h>
#include <stdint.h>

#define Hh 128
#define Aa 16
#define Tt 4
#define K1 144
#define K1P 160     // transposed-weight row length (k 144..159 zeroed)
#define W1T_LD 168  // LDS row stride: 336B -> bank advance 20 dw (2-way on fa reads, free)
#define WG_LD  136  // pad: stride 272B -> bank advance 4 dw -> 2-way (free)

typedef float f32x4 __attribute__((ext_vector_type(4)));
typedef __bf16 bf16x8 __attribute__((ext_vector_type(8)));
typedef unsigned short u16x8 __attribute__((ext_vector_type(8)));
typedef unsigned short u16x4 __attribute__((ext_vector_type(4)));
typedef unsigned short u16x2 __attribute__((ext_vector_type(2)));

static __device__ __forceinline__ unsigned short f2bf(float f) {
    unsigned u = __builtin_bit_cast(unsigned, f);
    u += 0x7fffu + ((u >> 16) & 1u);   // RNE
    return (unsigned short)(u >> 16);
}

static __device__ __forceinline__ float bf2f(unsigned short u) {
    return __builtin_bit_cast(float, (unsigned)u << 16);
}

static __device__ __forceinline__ bf16x8 pack8(const float* __restrict__ x) {
    f32x4 a = *(const f32x4*)x;
    f32x4 b = *(const f32x4*)(x + 4);
    u16x8 t;
    t[0] = f2bf(a[0]); t[1] = f2bf(a[1]); t[2] = f2bf(a[2]); t[3] = f2bf(a[3]);
    t[4] = f2bf(b[0]); t[5] = f2bf(b[1]); t[6] = f2bf(b[2]); t[7] = f2bf(b[3]);
    return __builtin_bit_cast(bf16x8, t);
}

static __device__ __forceinline__ bf16x8 zero_bf8() {
    u16x8 z = {0, 0, 0, 0, 0, 0, 0, 0};
    return __builtin_bit_cast(bf16x8, z);
}

// ============ fused bf16 pre-cast of h, W2, w_ih, w_hh (W1 handled by w1t_kernel)
__global__ void cast_all_kernel(
    const float* __restrict__ h, const float* __restrict__ W2,
    const float* __restrict__ wih, const float* __restrict__ whh,
    unsigned short* __restrict__ h_bf, unsigned short* __restrict__ W2bf,
    unsigned short* __restrict__ wihb, unsigned short* __restrict__ whhb,
    int n0, int n1, int n2, int n3)   // cumulative float4 boundaries
{
    int i = blockIdx.x * blockDim.x + threadIdx.x;
    if (i >= n3) return;
    const float* s; unsigned short* d; int off;
    if (i < n0)      { s = h;   d = h_bf; off = i; }
    else if (i < n1) { s = W2;  d = W2bf; off = i - n0; }
    else if (i < n2) { s = wih; d = wihb; off = i - n1; }
    else             { s = whh; d = whhb; off = i - n2; }
    f32x4 v = *(const f32x4*)(s + (size_t)off * 4);
    u16x4 o;
    o[0] = f2bf(v[0]); o[1] = f2bf(v[1]); o[2] = f2bf(v[2]); o[3] = f2bf(v[3]);
    *(u16x4*)(d + (size_t)off * 4) = o;
}

// ============ one-time transpose+cast: W1 [T][K1][H] f32 -> W1Tbf [T][H][K1P] bf16.
// k in [K1, K1P) zeroed (MUST be zero: LDS garbage could be NaN, NaN*0=NaN in MFMA).
// grid = T*10 blocks of 256; block (t, kb) covers k0 = kb*16.
__global__ void w1t_kernel(const float* __restrict__ W1, unsigned short* __restrict__ W1Tbf) {
    __shared__ float tile[16][129];   // 129: stride 1 mod 32 -> conflict-free transpose read
    const int b = blockIdx.x;
    const int t = b / 10, kb = b % 10;
    const int k0 = kb * 16;
    const int tid = threadIdx.x;
    for (int e = tid; e < 16 * 128; e += 256) {
        int k = e >> 7, n = e & 127;
        tile[k][n] = (k0 + k < K1) ? W1[((size_t)t * K1 + k0 + k) * Hh + n] : 0.f;
    }
    __syncthreads();
    for (int e = tid; e < 128 * 16; e += 256) {
        int n = e >> 4, kk = e & 15;
        W1Tbf[((size_t)t * Hh + n) * K1P + k0 + kk] = f2bf(tile[kk][n]);
    }
}

// ============ dual bucketing: bins [0,4N) by (type,dst), bins [4N,8N) by (type,src)
__global__ void hist_kernel(const int* __restrict__ et, const int* __restrict__ eidx,
                            int E, int N, int* __restrict__ cnt, unsigned* __restrict__ rank) {
    for (int i = blockIdx.x * blockDim.x + threadIdx.x; i < E; i += gridDim.x * blockDim.x) {
        int tt = et[i];
        unsigned rD = (unsigned)atomicAdd(&cnt[tt * N + eidx[E + i]], 1);
        unsigned rS = (unsigned)atomicAdd(&cnt[4 * N + tt * N + eidx[i]], 1);
        rank[i] = rD | (rS << 16);
    }
}

// per-1024-chunk block sums
__global__ void scanA_kernel(const int* __restrict__ deg2, int nb, int* __restrict__ bsum) {
    __shared__ int red[256];
    const int t = threadIdx.x;
    const int i0 = blockIdx.x * 1024 + t * 4;
    int s = 0;
    #pragma unroll
    for (int j = 0; j < 4; j++) if (i0 + j < nb) s += deg2[i0 + j];
    red[t] = s; __syncthreads();
    for (int d = 128; d > 0; d >>= 1) {
        if (t < d) red[t] += red[t + d];
        __syncthreads();
    }
    if (t == 0) bsum[blockIdx.x] = red[0];
}

// single-block exclusive scan of block sums (nblocks <= 512); also closes dst rowptr
__global__ void scanB_kernel(int* __restrict__ bsum, int nblocks,
                             int* __restrict__ rowptrD, int fourN, int E) {
    __shared__ int ts[512];
    const int t = threadIdx.x;
    int v = (t < nblocks) ? bsum[t] : 0;
    ts[t] = v; __syncthreads();
    for (int d = 1; d < 512; d <<= 1) {
        int x = (t >= d) ? ts[t - d] : 0;
        __syncthreads();
        ts[t] += x;
        __syncthreads();
    }
    if (t < nblocks) bsum[t] = ts[t] - v;
    if (t == 0) rowptrD[fourN] = E;
}

// per-chunk exclusive scan + global offset
__global__ void scanC_kernel(int* __restrict__ cur, int nb, int fourN,
                             const int* __restrict__ bsum, int* __restrict__ rowptrD) {
    __shared__ int ts[256];
    const int t = threadIdx.x;
    const int i0 = blockIdx.x * 1024 + t * 4;
    int v[4];
    #pragma unroll
    for (int j = 0; j < 4; j++) v[j] = (i0 + j < nb) ? cur[i0 + j] : 0;
    int s = v[0] + v[1] + v[2] + v[3];
    ts[t] = s; __syncthreads();
    for (int d = 1; d < 256; d <<= 1) {
        int x = (t >= d) ? ts[t - d] : 0;
        __syncthreads();
        ts[t] += x;
        __syncthreads();
    }
    int run = bsum[blockIdx.x] + ts[t] - s;
    #pragma unroll
    for (int j = 0; j < 4; j++) {
        if (i0 + j < nb) {
            if (i0 + j < fourN) rowptrD[i0 + j] = run;
            cur[i0 + j] = run;
            run += v[j];
        }
    }
}

// atomic-free placement
__global__ void fill2_kernel(const int* __restrict__ et, const int* __restrict__ eidx,
                             int E, int N, const int* __restrict__ binstart,
                             const unsigned* __restrict__ rank, int4* __restrict__ rec) {
    for (int i = blockIdx.x * blockDim.x + threadIdx.x; i < E; i += gridDim.x * blockDim.x) {
        int tt = et[i];
        int d = eidx[E + i], s = eidx[i];
        unsigned r = rank[i];
        int posD = binstart[tt * N + d] + (int)(r & 0xffffu);
        int posS = binstart[4 * N + tt * N + s] + (int)(r >> 16) - E;
        rec[posS] = make_int4(s, i, posD, 0);
    }
}

// ---------------- layer 1: edges in (type,src) order -> sequential h gather;
// 8 waves = 4 edge-groups x 2 channel-halves. Each wave: 32 edges x 64 channels,
// acc[4][2] (32 regs) so total regs fit 6 waves/SIMD -> 3 blocks/CU with 43.5KB LDS.
// Direct per-lane stores: lane (q,l15) reg i of acc[mt][g] holds channel
// (mh*4+mt)*16+q*4+i of edge l15; each lane has its edge's posD from rec. The two
// channel-half waves write disjoint 128B halves of each 256B row -> full dirty lines.
// Staging is a pure coalesced u16x8 copy from the pre-transposed W1Tbf.
__global__ __launch_bounds__(512) void l1_kernel(
    const unsigned short* __restrict__ h_bf, const int4* __restrict__ rec,
    const float* __restrict__ eattr, const unsigned short* __restrict__ W1Tbf,
    const float* __restrict__ b1, const int* __restrict__ rowptrD,
    unsigned short* __restrict__ Yg, int N)
{
    __shared__ unsigned short W1T[128 * W1T_LD];   // cols 0..159 valid (144..159 zero)
    __shared__ float b1s[128];
    const int t = blockIdx.x & 3;
    const int lb = blockIdx.x >> 2;
    const int nbk = gridDim.x >> 2;
    const int tid = threadIdx.x;

    for (int idx = tid; idx < (Hh * K1P) / 8; idx += 512) {
        int n = idx / (K1P / 8), c = (idx % (K1P / 8)) * 8;
        *(u16x8*)&W1T[n * W1T_LD + c] =
            *(const u16x8*)&W1Tbf[((size_t)t * Hh + n) * K1P + c];
    }
    if (tid < 128) b1s[tid] = b1[t * Hh + tid];
    __syncthreads();

    const int tstart = rowptrD[t * N];
    const int tend = rowptrD[(t + 1) * N];
    const int cnt = tend - tstart;
    const int ntiles = (cnt + 127) >> 7;       // 128 edges per block-tile
    const int lane = tid & 63;
    const int eg = tid >> 7;                   // edge group 0..3
    const int mh = (tid >> 6) & 1;             // channel half
    const int l15 = lane & 15, q = lane >> 4;
    const int mtb = mh * 4;

    for (int tile = lb; tile < ntiles; tile += nbk) {
        const int p0 = tstart + tile * 128 + eg * 32;
        const int pa = p0 + l15, pb = p0 + 16 + l15;
        const bool va = pa < tend, vb = pb < tend;
        const int4 ra = rec[va ? pa : tstart];
        const int4 rb = rec[vb ? pb : tstart];
        const unsigned short* __restrict__ hA = h_bf + (size_t)ra.x * Hh;
        const unsigned short* __restrict__ hB = h_bf + (size_t)rb.x * Hh;

        f32x4 acc[4][2];
        #pragma unroll
        for (int mt = 0; mt < 4; mt++) {
            acc[mt][0] = (f32x4){0.f, 0.f, 0.f, 0.f};
            acc[mt][1] = (f32x4){0.f, 0.f, 0.f, 0.f};
        }

        #pragma unroll
        for (int ks = 0; ks < 5; ks++) {
            const int k0 = ks * 32;
            bf16x8 fb_a, fb_b;
            if (ks < 4) {
                fb_a = __builtin_bit_cast(bf16x8, *(const u16x8*)(hA + k0 + q * 8));
                fb_b = __builtin_bit_cast(bf16x8, *(const u16x8*)(hB + k0 + q * 8));
            } else if (q < 2) {
                fb_a = pack8(eattr + (size_t)ra.y * Aa + q * 8);
                fb_b = pack8(eattr + (size_t)rb.y * Aa + q * 8);
            } else {
                fb_a = zero_bf8();
                fb_b = zero_bf8();
            }
            #pragma unroll
            for (int mt = 0; mt < 4; mt++) {
                bf16x8 fa = *(const bf16x8*)&W1T[((mtb + mt) * 16 + l15) * W1T_LD + k0 + q * 8];
                acc[mt][0] = __builtin_amdgcn_mfma_f32_16x16x32_bf16(fa, fb_a, acc[mt][0], 0, 0, 0);
                acc[mt][1] = __builtin_amdgcn_mfma_f32_16x16x32_bf16(fa, fb_b, acc[mt][1], 0, 0, 0);
            }
        }

        // epilogue: bias+relu+cvt, direct 8B/lane stores; 4 q-lanes = one 32B sector
        #pragma unroll
        for (int g = 0; g < 2; g++) {
            if (g ? vb : va) {
                const int yp = g ? rb.z : ra.z;
                unsigned short* __restrict__ o = Yg + (size_t)yp * Hh + mtb * 16 + q * 4;
                #pragma unroll
                for (int mt = 0; mt < 4; mt++) {
                    f32x4 bias = *(const f32x4*)&b1s[(mtb + mt) * 16 + q * 4];
                    u16x4 y;
                    #pragma unroll
                    for (int i = 0; i < 4; i++) {
                        float v = acc[mt][g][i] + bias[i];
                        y[i] = f2bf(v > 0.f ? v : 0.f);
                    }
                    *(u16x4*)(o + mt * 16) = y;
                }
            }
        }
    }
}

// ---------------- fused segment-sum + second GEMM (unchanged)
__global__ __launch_bounds__(256) void zgemm_kernel(
    const unsigned short* __restrict__ Yg, const int* __restrict__ rowptrD,
    const unsigned short* __restrict__ W2bf, const float* __restrict__ b2,
    unsigned short* __restrict__ msgb, int N)
{
    __shared__ unsigned short W2T[128 * WG_LD];
    __shared__ float b2s[512];
    __shared__ int cntS[4 * 64];
    const int tid = threadIdx.x;
    const int w = tid >> 6, lane = tid & 63;
    const int l15 = lane & 15, q = lane >> 4;
    const int nodebase = blockIdx.x * 64 + w * 16;
    const int nA = min(nodebase + l15, N - 1);

    if (tid < 512) {
        b2s[tid] = b2[tid];
        b2s[tid + 256] = b2[tid + 256];
    }

    f32x4 acc[8];
    #pragma unroll
    for (int ct = 0; ct < 8; ct++) acc[ct] = (f32x4){0.f, 0.f, 0.f, 0.f};

    for (int t = 0; t < Tt; t++) {
        __syncthreads();
        for (int idx = tid; idx < Hh * Hh; idx += 256) {
            int k = idx >> 7, n = idx & 127;
            W2T[n * WG_LD + k] = W2bf[((size_t)t * Hh + k) * Hh + n];
        }
        __syncthreads();

        const int seg = rowptrD[(size_t)t * N + nA];
        const int len = rowptrD[(size_t)t * N + nA + 1] - seg;
        cntS[w * 64 + t * 16 + l15] = len;

        float asum[32];
        #pragma unroll
        for (int i = 0; i < 32; i++) asum[i] = 0.f;
        for (int j = 0; j < len; j++) {
            const unsigned short* __restrict__ yr = Yg + (size_t)(seg + j) * Hh;
            #pragma unroll
            for (int ks = 0; ks < 4; ks++) {
                u16x8 yv = *(const u16x8*)(yr + ks * 32 + q * 8);
                #pragma unroll
                for (int e = 0; e < 8; e++) asum[ks * 8 + e] += bf2f(yv[e]);
            }
        }

        #pragma unroll
        for (int ks = 0; ks < 4; ks++) {
            u16x8 fr;
            #pragma unroll
            for (int e = 0; e < 8; e++) fr[e] = f2bf(asum[ks * 8 + e]);
            bf16x8 fa = __builtin_bit_cast(bf16x8, fr);
            #pragma unroll
            for (int ct = 0; ct < 8; ct++) {
                bf16x8 fb = *(const bf16x8*)&W2T[(ct * 16 + l15) * WG_LD + ks * 32 + q * 8];
                acc[ct] = __builtin_amdgcn_mfma_f32_16x16x32_bf16(fa, fb, acc[ct], 0, 0, 0);
            }
        }
    }
    __syncthreads();

    #pragma unroll
    for (int ct = 0; ct < 8; ct++) {
        const int c = ct * 16 + l15;
        #pragma unroll
        for (int i = 0; i < 4; i++) {
            int node = nodebase + q * 4 + i;
            if (node < N) {
                float bias = 0.f;
                #pragma unroll
                for (int t = 0; t < Tt; t++)
                    bias += (float)cntS[w * 64 + t * 16 + q * 4 + i] * b2s[t * 128 + c];
                msgb[(size_t)node * Hh + c] = f2bf(acc[ct][i] + bias);
            }
        }
    }
}

// ---------------- GRU: fragments hoisted (msg/h read ONCE, bf16), vectorized staging
__global__ __launch_bounds__(512) void gru_kernel(
    const float* __restrict__ h, const unsigned short* __restrict__ h_bf,
    const unsigned short* __restrict__ msgb,
    const unsigned short* __restrict__ wihb, const unsigned short* __restrict__ whhb,
    const float* __restrict__ b_ih, const float* __restrict__ b_hh,
    float* __restrict__ out, int N)
{
    __shared__ unsigned short Wg[128 * WG_LD];
    const int tid = threadIdx.x;
    const int w = tid >> 6, lane = tid & 63;
    const int l15 = lane & 15, q = lane >> 4;
    const int nodebase = blockIdx.x * 128 + w * 16;
    const int nA = min(nodebase + l15, N - 1);

    bf16x8 fm[4], fh[4];
    #pragma unroll
    for (int ks = 0; ks < 4; ks++) {
        fm[ks] = __builtin_bit_cast(bf16x8, *(const u16x8*)(msgb + (size_t)nA * Hh + ks * 32 + q * 8));
        fh[ks] = __builtin_bit_cast(bf16x8, *(const u16x8*)(h_bf + (size_t)nA * Hh + ks * 32 + q * 8));
    }

    f32x4 gr[8], gz[8], gin[8], ghn[8];
    #pragma unroll
    for (int ct = 0; ct < 8; ct++) {
        gr[ct] = (f32x4){0.f, 0.f, 0.f, 0.f};
        gz[ct] = (f32x4){0.f, 0.f, 0.f, 0.f};
        gin[ct] = (f32x4){0.f, 0.f, 0.f, 0.f};
        ghn[ct] = (f32x4){0.f, 0.f, 0.f, 0.f};
    }

    auto stage = [&](const unsigned short* __restrict__ Ws, int gate) {
        __syncthreads();
        for (int idx = tid; idx < (Hh * Hh) / 8; idx += 512) {
            int o = idx >> 4, k8 = (idx & 15) * 8;
            *(u16x8*)&Wg[o * WG_LD + k8] =
                *(const u16x8*)&Ws[(size_t)gate * Hh * Hh + o * Hh + k8];
        }
        __syncthreads();
    };
    auto matmul = [&](f32x4* acc, const bf16x8* fa) {
        #pragma unroll
        for (int ks = 0; ks < 4; ks++) {
            #pragma unroll
            for (int ct = 0; ct < 8; ct++) {
                bf16x8 fb = *(const bf16x8*)&Wg[(ct * 16 + l15) * WG_LD + ks * 32 + q * 8];
                acc[ct] = __builtin_amdgcn_mfma_f32_16x16x32_bf16(fa[ks], fb, acc[ct], 0, 0, 0);
            }
        }
    };

    stage(wihb, 0); matmul(gr, fm);
    stage(whhb, 0); matmul(gr, fh);
    stage(wihb, 1); matmul(gz, fm);
    stage(whhb, 1); matmul(gz, fh);
    stage(wihb, 2); matmul(gin, fm);
    stage(whhb, 2); matmul(ghn, fh);

    #pragma unroll
    for (int ct = 0; ct < 8; ct++) {
        int c = ct * 16 + l15;
        float bir = b_ih[c],       bhr = b_hh[c];
        float biz = b_ih[128 + c], bhz = b_hh[128 + c];
        float bin = b_ih[256 + c], bhn = b_hh[256 + c];
        #pragma unroll
        for (int i = 0; i < 4; i++) {
            int node = nodebase + q * 4 + i;
            if (node < N) {
                float rv = 1.f / (1.f + __expf(-(gr[ct][i] + bir + bhr)));
                float zv = 1.f / (1.f + __expf(-(gz[ct][i] + biz + bhz)));
                float npre = gin[ct][i] + bin + rv * (ghn[ct][i] + bhn);
                float e2 = __expf(-2.f * npre);
                float nv = (1.f - e2) / (1.f + e2);
                float hv = h[(size_t)node * Hh + c];
                out[(size_t)node * Hh + c] = (1.f - zv) * nv + zv * hv;
            }
        }
    }
}

static inline size_t align256(size_t x) { return (x + 255) & ~(size_t)255; }

extern "C" void kernel_launch(void* const* d_in, const int* in_sizes, int n_in,
                              void* d_out, int out_size, void* d_ws, size_t ws_size,
                              hipStream_t stream)
{
    const float* h     = (const float*)d_in[0];
    const int*   eidx  = (const int*)d_in[1];
    const int*   et    = (const int*)d_in[2];
    const float* eattr = (const float*)d_in[3];
    const float* W1    = (const float*)d_in[4];
    const float* b1    = (const float*)d_in[5];
    const float* W2    = (const float*)d_in[6];
    const float* b2    = (const float*)d_in[7];
    const float* w_ih  = (const float*)d_in[8];
    const float* w_hh  = (const float*)d_in[9];
    const float* b_ih  = (const float*)d_in[10];
    const float* b_hh  = (const float*)d_in[11];

    const int N = in_sizes[0] / Hh;
    const int E = in_sizes[1] / 2;
    const int nb = 8 * N;
    const int sblocks = (nb + 1023) / 1024;

    char* p = (char*)d_ws;
    unsigned short* msgb = (unsigned short*)p; p += align256((size_t)N * Hh * sizeof(unsigned short));
    unsigned short* Yg = (unsigned short*)p;   p += align256((size_t)E * Hh * sizeof(unsigned short));
    int4* rec = (int4*)p;               p += align256((size_t)E * sizeof(int4));
    unsigned* rank = (unsigned*)p;      p += align256((size_t)E * sizeof(unsigned));
    int* rowptrD = (int*)p;             p += align256(((size_t)4 * N + 1) * sizeof(int));
    int* cur = (int*)p;                 p += align256((size_t)nb * sizeof(int));
    int* bsum = (int*)p;                p += align256(1024 * sizeof(int));
    unsigned short* h_bf = (unsigned short*)p; p += align256((size_t)N * Hh * sizeof(unsigned short));
    unsigned short* W1Tbf = (unsigned short*)p; p += align256((size_t)Tt * Hh * K1P * sizeof(unsigned short));
    unsigned short* W2bf = (unsigned short*)p; p += align256((size_t)Tt * Hh * Hh * sizeof(unsigned short));
    unsigned short* wihb = (unsigned short*)p; p += align256((size_t)3 * Hh * Hh * sizeof(unsigned short));
    unsigned short* whhb = (unsigned short*)p; p += align256((size_t)3 * Hh * Hh * sizeof(unsigned short));

    hipMemsetAsync(cur, 0, (size_t)nb * sizeof(int), stream);

    {
        int n4h = N * Hh / 4, n42 = Tt * Hh * Hh / 4, n4g = 3 * Hh * Hh / 4;
        int c0 = n4h, c1 = c0 + n42, c2 = c1 + n4g, c3 = c2 + n4g;
        cast_all_kernel<<<(c3 + 255) / 256, 256, 0, stream>>>(
            h, W2, w_ih, w_hh, h_bf, W2bf, wihb, whhb, c0, c1, c2, c3);
    }
    w1t_kernel<<<Tt * 10, 256, 0, stream>>>(W1, W1Tbf);

    hist_kernel<<<1024, 256, 0, stream>>>(et, eidx, E, N, cur, rank);
    scanA_kernel<<<sblocks, 256, 0, stream>>>(cur, nb, bsum);
    scanB_kernel<<<1, 512, 0, stream>>>(bsum, sblocks, rowptrD, 4 * N, E);
    scanC_kernel<<<sblocks, 256, 0, stream>>>(cur, nb, 4 * N, bsum, rowptrD);
    fill2_kernel<<<1024, 256, 0, stream>>>(et, eidx, E, N, cur, rank, rec);

    l1_kernel<<<2048, 512, 0, stream>>>(h_bf, rec, eattr, W1Tbf, b1, rowptrD, Yg, N);
    zgemm_kernel<<<(N + 63) / 64, 256, 0, stream>>>(Yg, rowptrD, W2bf, b2, msgb, N);

    int gblocks = (N + 127) / 128;
    gru_kernel<<<gblocks, 512, 0, stream>>>(h, h_bf, msgb, wihb, whhb, b_ih, b_hh, (float*)d_out, N);
}